// Round 2
// baseline (45327.084 us; speedup 1.0000x reference)
//
#include <hip/hip_runtime.h>
#include <hip/hip_cooperative_groups.h>

namespace cg = cooperative_groups;

// Problem dims
#define B_    128
#define H_    512
#define T_    512
#define L_    3
#define FIN_  64
#define FOUT_ 8
#define WOUT_ 64
#define G4H_  2048   // 4*H_

// Launch shape: 64 blocks per layer, each owns 8 H-columns (=32 gate rows).
#define NBLK  192
#define NTHR  256

struct Params {
  const float *x, *eWih0, *eWih, *eWhh, *ebih, *ebhh;
  const float *dWih0, *dWih, *dWhh, *dbih, *dbhh, *fcw, *fcb;
  float *out; float *ws;
};

__device__ __forceinline__ float sigm(float x) { return 1.0f / (1.0f + __expf(-x)); }
__device__ __forceinline__ float tanhf_(float x) {
  float e = __expf(-2.0f * fabsf(x));
  return copysignf((1.0f - e) / (1.0f + e), x);
}

// Stage this block's 32 gate rows (4 gates x 8 cols) of Wi|Wh into LDS,
// transposed to [k][row] so GEMM reads are ds_read_b128 with lane-broadcast.
__device__ __forceinline__ void stage_w(float* Wl, const float* Wi, int Kin,
                                        const float* Wh, int j0) {
  const int tid = threadIdx.x;
  for (int r = 0; r < 32; ++r) {
    const int gr = (r >> 3) * H_ + j0 + (r & 7);
    const float* s0 = Wi + (size_t)gr * Kin;
    for (int k = tid; k < Kin; k += NTHR) Wl[k * 32 + r] = s0[k];
    const float* s1 = Wh + (size_t)gr * H_;
    for (int k = tid; k < H_; k += NTHR) Wl[(Kin + k) * 32 + r] = s1[k];
  }
}

// One LSTM cell step for this block's 8 columns.
// GEMM: out[128 batch][32 rows], K = K0 (layer input) + 512 (own hidden).
// Thread tile 4 batch x 4 rows: tr=tid>>5 (rows 4tr..), tb=tid&31 (batch 4tb..).
// Elementwise: jj=tid>>5 (column), bc=(tid&31)*4 (batch quad); creg[4] holds c.
template <int K0, bool FC>
__device__ __forceinline__ void cell(const float* __restrict__ Wl,
                                     float* __restrict__ gl,
                                     const float* __restrict__ in0,
                                     const float* __restrict__ inH,
                                     float* __restrict__ hout,
                                     const float* __restrict__ bias,
                                     float* __restrict__ creg,
                                     const float* __restrict__ fcwl,
                                     float* __restrict__ predt) {
  const int tid = threadIdx.x;
  const int tr = tid >> 5, tb = tid & 31;
  float acc[4][4];
  #pragma unroll
  for (int i = 0; i < 4; ++i)
    #pragma unroll
    for (int j = 0; j < 4; ++j) acc[i][j] = bias[i];

  {
    const float* wp = Wl + 4 * tr;
    const float* ap = in0 + 4 * tb;
    #pragma unroll 8
    for (int k = 0; k < K0; ++k) {
      float4 w = *(const float4*)(wp + k * 32);
      float4 a = *(const float4*)(ap + k * B_);
      float wv[4] = {w.x, w.y, w.z, w.w};
      float av[4] = {a.x, a.y, a.z, a.w};
      #pragma unroll
      for (int i = 0; i < 4; ++i)
        #pragma unroll
        for (int j = 0; j < 4; ++j) acc[i][j] = fmaf(wv[i], av[j], acc[i][j]);
    }
  }
  {
    const float* wp = Wl + K0 * 32 + 4 * tr;
    const float* ap = inH + 4 * tb;
    #pragma unroll 8
    for (int k = 0; k < H_; ++k) {
      float4 w = *(const float4*)(wp + k * 32);
      float4 a = *(const float4*)(ap + k * B_);
      float wv[4] = {w.x, w.y, w.z, w.w};
      float av[4] = {a.x, a.y, a.z, a.w};
      #pragma unroll
      for (int i = 0; i < 4; ++i)
        #pragma unroll
        for (int j = 0; j < 4; ++j) acc[i][j] = fmaf(wv[i], av[j], acc[i][j]);
    }
  }
  // gates -> LDS (remap from GEMM tile to per-column layout)
  #pragma unroll
  for (int i = 0; i < 4; ++i) {
    *(float4*)&gl[(4 * tr + i) * B_ + 4 * tb] =
        make_float4(acc[i][0], acc[i][1], acc[i][2], acc[i][3]);
  }
  __syncthreads();

  const int jj = tid >> 5;
  const int bc = (tid & 31) * 4;
  float4 v;
  v = *(const float4*)&gl[(jj) * B_ + bc];      float gi[4] = {v.x, v.y, v.z, v.w};
  v = *(const float4*)&gl[(8 + jj) * B_ + bc];  float gf[4] = {v.x, v.y, v.z, v.w};
  v = *(const float4*)&gl[(16 + jj) * B_ + bc]; float gg[4] = {v.x, v.y, v.z, v.w};
  v = *(const float4*)&gl[(24 + jj) * B_ + bc]; float go[4] = {v.x, v.y, v.z, v.w};
  float hv[4];
  #pragma unroll
  for (int j = 0; j < 4; ++j) {
    float cc = sigm(gf[j]) * creg[j] + sigm(gi[j]) * tanhf_(gg[j]);
    creg[j] = cc;
    hv[j] = sigm(go[j]) * tanhf_(cc);
  }
  *(float4*)&hout[jj * B_ + bc] = make_float4(hv[0], hv[1], hv[2], hv[3]);

  if (FC) {
    // fc partial: this block's 8 columns' contribution to pred[f][b].
    __syncthreads();                  // everyone done reading gates from gl
    for (int i = tid; i < FOUT_ * B_; i += NTHR) gl[i] = 0.0f;
    __syncthreads();
    #pragma unroll
    for (int f = 0; f < FOUT_; ++f) {
      float w = fcwl[f * 8 + jj];
      #pragma unroll
      for (int j = 0; j < 4; ++j) atomicAdd(&gl[f * B_ + bc + j], hv[j] * w);
    }
    __syncthreads();
    for (int i = tid; i < FOUT_ * B_; i += NTHR) atomicAdd(&predt[i], gl[i]);
  }
}

__global__ void __launch_bounds__(NTHR, 1) lstm_all(Params p) {
  // LDS: weights [K<=1024][32] = 128KB, gates 16KB, fc slice 256B -> 144.3KB/CU
  __shared__ __align__(16) float Wl[1024 * 32];
  __shared__ __align__(16) float gl[32 * B_];
  __shared__ float fcwl[FOUT_ * 8];

  const int tid = threadIdx.x;
  const int bid = blockIdx.x;
  const int layer = bid >> 6;          // 0..2
  const int j0 = (bid & 63) * 8;       // first owned H-column

  float* xT = p.ws;                               // [T][FIN][B]
  float* hb = xT + (size_t)T_ * FIN_ * B_;        // [3][2][H][B]
  float* pr = hb + (size_t)L_ * 2 * H_ * B_;      // [2][FOUT][B]

  cg::grid_group grid = cg::this_grid();

  // ---- Phase A: init (ws is poisoned before every call) ----
  for (int i = bid * NTHR + tid; i < L_ * 2 * H_ * B_; i += NBLK * NTHR) hb[i] = 0.0f;
  if (bid == 0) {
    for (int i = tid; i < FOUT_ * B_; i += NTHR) {
      int f = i >> 7, b = i & 127;
      pr[i] = p.fcb[f];                                        // pred[0] accumulator base
      // dec_in = x[:, -1, :FOUT] -> feature FIN-1, times 0..7
      pr[FOUT_ * B_ + i] = p.x[(size_t)b * FIN_ * T_ + (size_t)(FIN_ - 1) * T_ + f];
    }
  }
  for (int i = bid * NTHR + tid; i < T_ * FIN_ * B_; i += NBLK * NTHR) {
    int b = i & 127, f = (i >> 7) & 63, t = i >> 13;
    xT[i] = p.x[(size_t)b * FIN_ * T_ + (size_t)f * T_ + t];
  }

  float bias[4];
  {  // stage encoder weights + bias regs
    const float* Wi = (layer == 0) ? p.eWih0 : p.eWih + (size_t)(layer - 1) * G4H_ * H_;
    if (layer == 0) stage_w(Wl, Wi, FIN_, p.eWhh + (size_t)layer * G4H_ * H_, j0);
    else            stage_w(Wl, Wi, H_,   p.eWhh + (size_t)layer * G4H_ * H_, j0);
    int tr = tid >> 5;
    #pragma unroll
    for (int i = 0; i < 4; ++i) {
      int r = 4 * tr + i, gr = (r >> 3) * H_ + j0 + (r & 7);
      bias[i] = p.ebih[layer * G4H_ + gr] + p.ebhh[layer * G4H_ + gr];
    }
  }
  grid.sync();

  float creg[4] = {0.0f, 0.0f, 0.0f, 0.0f};

  // ---- Encoder: diagonal pipeline, layer l does t = s - l ----
  for (int s = 0; s < T_ + L_ - 1; ++s) {
    int t = s - layer;
    if (t >= 0 && t < T_) {
      const float* inH = hb + ((size_t)layer * 2 + ((s - 1) & 1)) * H_ * B_;
      float* ho = hb + ((size_t)layer * 2 + (s & 1)) * H_ * B_ + (size_t)j0 * B_;
      if (layer == 0) {
        cell<FIN_, false>(Wl, gl, xT + (size_t)t * FIN_ * B_, inH, ho, bias, creg,
                          nullptr, nullptr);
      } else {
        const float* in0 = hb + ((size_t)(layer - 1) * 2 + ((s - 1) & 1)) * H_ * B_;
        cell<H_, false>(Wl, gl, in0, inH, ho, bias, creg, nullptr, nullptr);
      }
    }
    grid.sync();
  }

  // ---- Restage decoder weights (block-local) ----
  {
    if (layer == 0) stage_w(Wl, p.dWih0, FOUT_, p.dWhh + (size_t)layer * G4H_ * H_, j0);
    else stage_w(Wl, p.dWih + (size_t)(layer - 1) * G4H_ * H_, H_,
                 p.dWhh + (size_t)layer * G4H_ * H_, j0);
    int tr = tid >> 5;
    #pragma unroll
    for (int i = 0; i < 4; ++i) {
      int r = 4 * tr + i, gr = (r >> 3) * H_ + j0 + (r & 7);
      bias[i] = p.dbih[layer * G4H_ + gr] + p.dbhh[layer * G4H_ + gr];
    }
    if (layer == 2 && tid < 64)
      fcwl[tid] = p.fcw[(size_t)(tid >> 3) * H_ + j0 + (tid & 7)];
  }
  __syncthreads();

  // ---- Decoder: sequential, 3 sync'd phases per step ----
  // Parities: layer l at step d writes h[l][(d+l)&1], reads own (d-1+l)&1,
  // reads below (d+l-1)&1 — consistent with encoder finals (511+l)&1.
  for (int d = 0; d < WOUT_; ++d) {
    if (layer == 0) {
      const float* in0 = pr + (size_t)((d + 1) & 1) * FOUT_ * B_;
      const float* inH = hb + (size_t)((d + 1) & 1) * H_ * B_;              // l=0, par (d-1)&1
      float* ho = hb + (size_t)(d & 1) * H_ * B_ + (size_t)j0 * B_;         // write d&1
      cell<FOUT_, false>(Wl, gl, in0, inH, ho, bias, creg, nullptr, nullptr);
    }
    grid.sync();
    if (bid == 128) {
      // layer-2 block, idle in phase 2: pr[(d+1)&1] is dead (consumed by layer 0
      // in phase 1). Emit pred[d-1] from it (d>=1), then ALWAYS reset it to fc_b
      // so it is a clean accumulator for step d+1's FC. (At d==0 this retires the
      // dec_in buffer — the round-1 bug was leaving dec_in in the accumulator.)
      int q = (d + 1) & 1;
      for (int i = tid; i < FOUT_ * B_; i += NTHR) {
        int f = i >> 7, b = i & 127;
        if (d >= 1)
          p.out[(size_t)b * FOUT_ * WOUT_ + (size_t)f * WOUT_ + (d - 1)] =
              pr[(size_t)q * FOUT_ * B_ + i];
        pr[(size_t)q * FOUT_ * B_ + i] = p.fcb[f];
      }
    }
    if (layer == 1) {
      const float* in0 = hb + (size_t)(d & 1) * H_ * B_;                     // h0 this step
      const float* inH = hb + (size_t)(2 + (d & 1)) * H_ * B_;               // own prev
      float* ho = hb + (size_t)(2 + ((d + 1) & 1)) * H_ * B_ + (size_t)j0 * B_;
      cell<H_, false>(Wl, gl, in0, inH, ho, bias, creg, nullptr, nullptr);
    }
    grid.sync();
    if (layer == 2) {
      const float* in0 = hb + (size_t)(2 + ((d + 1) & 1)) * H_ * B_;         // h1 this step
      const float* inH = hb + (size_t)(4 + ((d + 1) & 1)) * H_ * B_;         // own prev
      float* ho = hb + (size_t)(4 + (d & 1)) * H_ * B_ + (size_t)j0 * B_;
      cell<H_, true>(Wl, gl, in0, inH, ho, bias, creg, fcwl,
                     pr + (size_t)(d & 1) * FOUT_ * B_);
    }
    grid.sync();
  }

  if (bid == 0) {  // last prediction (step 63, parity 1)
    for (int i = tid; i < FOUT_ * B_; i += NTHR) {
      int f = i >> 7, b = i & 127;
      p.out[(size_t)b * FOUT_ * WOUT_ + (size_t)f * WOUT_ + (WOUT_ - 1)] =
          pr[(size_t)FOUT_ * B_ + i];
    }
  }
}

extern "C" void kernel_launch(void* const* d_in, const int* in_sizes, int n_in,
                              void* d_out, int out_size, void* d_ws, size_t ws_size,
                              hipStream_t stream) {
  (void)in_sizes; (void)n_in; (void)out_size; (void)ws_size;
  Params p;
  p.x     = (const float*)d_in[0];
  p.eWih0 = (const float*)d_in[1];
  p.eWih  = (const float*)d_in[2];
  p.eWhh  = (const float*)d_in[3];
  p.ebih  = (const float*)d_in[4];
  p.ebhh  = (const float*)d_in[5];
  p.dWih0 = (const float*)d_in[6];
  p.dWih  = (const float*)d_in[7];
  p.dWhh  = (const float*)d_in[8];
  p.dbih  = (const float*)d_in[9];
  p.dbhh  = (const float*)d_in[10];
  p.fcw   = (const float*)d_in[11];
  p.fcb   = (const float*)d_in[12];
  p.out   = (float*)d_out;
  p.ws    = (float*)d_ws;
  // ws usage: xT 16MB + h 1.5MB + pred 8KB ~= 17.6MB, fp32.
  void* args[] = { &p };
  hipLaunchCooperativeKernel((const void*)lstm_all, dim3(NBLK), dim3(NTHR), args, 0,
                             stream);
}

// Round 6
// 28768.155 us; speedup vs baseline: 1.5756x; 1.5756x over previous
//
#include <hip/hip_runtime.h>
#include <hip/hip_cooperative_groups.h>

namespace cg = cooperative_groups;

// Problem dims
#define B_    128
#define H_    512
#define T_    512
#define FIN_  64
#define FOUT_ 8
#define WOUT_ 64
#define G4H_  2048   // 4*H_

// 64 blocks per layer (8 h-cols each = 32 gate rows), 512 threads (8 waves).
#define NBLK  192
#define NTHR  512

typedef __attribute__((ext_vector_type(8))) _Float16 half8;
typedef __attribute__((ext_vector_type(4))) float f32x4;
typedef unsigned short u16;
typedef unsigned int u32;

#define LOSCALE   4096.0f          // 2^12: lifts fp16 lo-plane out of subnormals
#define LOINV     0.000244140625f  // 2^-12

struct Params {
  const float *x, *eWih0, *eWih, *eWhh, *ebih, *ebhh;
  const float *dWih0, *dWih, *dWhh, *dbih, *dbhh, *fcw, *fcb;
  float *out; float *ws;
};

__device__ __forceinline__ float sigm(float x) { return 1.0f / (1.0f + __expf(-x)); }
__device__ __forceinline__ float tanhf_(float x) {
  float e = __expf(-2.0f * fabsf(x));
  return copysignf((1.0f - e) / (1.0f + e), x);
}
__device__ __forceinline__ u16 h2u(_Float16 h) {
  union { _Float16 f; u16 u; } v; v.f = h; return v.u;
}
// fp32 -> fp16 hi + scaled lo (lo = 2^12 * residual, fp16-normal for our ranges)
__device__ __forceinline__ void split16(float w, u16& hi, u16& lo) {
  _Float16 h = (_Float16)w;
  _Float16 l = (_Float16)((w - (float)h) * LOSCALE);
  hi = h2u(h); lo = h2u(l);
}

// Stage this block's 32 gate rows of [Wi | Wh] into LDS as fp16 hi/lo planes,
// B-fragment order: Wb[n][k], with 16B-chunk XOR swizzle (chunk ^= n&7) so the
// MFMA B-reads (16 rows x same chunk) are ~2-way instead of 16-way conflicted.
__device__ void stage_w(u16* WbHi, u16* WbLo, const float* Wi, int Kreal, int K0pad,
                        const float* Wh, int j0) {
  const int rowlen = K0pad + H_;
  for (int n = 0; n < 32; ++n) {
    const int gr = (n >> 3) * H_ + j0 + (n & 7);
    const float* s0 = Wi + (size_t)gr * Kreal;
    const float* s1 = Wh + (size_t)gr * H_;
    const int sw = (n & 7) << 3;
    for (int k = threadIdx.x; k < rowlen; k += NTHR) {
      float w = (k < K0pad) ? ((k < Kreal) ? s0[k] : 0.0f) : s1[k - K0pad];
      u16 hi, lo; split16(w, hi, lo);
      int kk = k ^ sw;                    // XOR lives in bits 3..5 (chunk bits)
      WbHi[n * 1024 + kk] = hi;
      WbLo[n * 1024 + kk] = lo;
    }
  }
}

// One LSTM cell step for this block's 8 h-columns.
// GEMM D[128 batch][32 gate-rows] via mfma_f32_16x16x32_f16, fp16 split:
//   acc_hi += Ah*Wh ; acc_lo += Al*Wh + Ah*Wl ; D = acc_hi + 2^-12 * acc_lo.
// Wave w owns batches 16w..16w+15 (1 M-tile) x both N-tiles.
// A-frag: lane provides A[m=lane&15][k=(lane>>4)*8+j]  (16B load, [B][K] layout)
// B-frag: lane provides B[k=(lane>>4)*8+j][n=lane&15]  (LDS row n, swizzled chunk)
// D: n = lane&15, m = (lane>>4)*4 + reg  -> 4 consecutive batches = ds_write_b128.
template <int NC0, bool DEC0, bool FC>
__device__ __forceinline__ void cell(
    const u16* __restrict__ WbHi, const u16* __restrict__ WbLo,
    float* __restrict__ gl, float* __restrict__ predl,
    const float* __restrict__ bias_s, const float* __restrict__ fcw_s,
    const u16* __restrict__ i0h, const u16* __restrict__ i0l, const int ld0,
    const float* __restrict__ pr_in,
    const u16* __restrict__ iHh, const u16* __restrict__ iHl,
    u16* __restrict__ ohh, u16* __restrict__ ohl, const int j0,
    float* __restrict__ creg, float* __restrict__ pr_out) {
  const int tid = threadIdx.x;
  const int lane = tid & 63, lr = lane & 15, lg = lane >> 4;
  const int m0 = (tid >> 6) << 4;      // wave's batch base
  const int mb = m0 + lr;              // this lane's A batch row
  const int sw = (lr & 7) << 3;        // swizzle (same for rows lr and 16+lr)

  f32x4 acc0 = {0.f, 0.f, 0.f, 0.f}, acc1 = {0.f, 0.f, 0.f, 0.f};
  f32x4 acc0L = {0.f, 0.f, 0.f, 0.f}, acc1L = {0.f, 0.f, 0.f, 0.f};

  const u16* bh0 = WbHi + lr * 1024;
  const u16* bl0 = WbLo + lr * 1024;
  const u16* bh1 = WbHi + (16 + lr) * 1024;
  const u16* bl1 = WbLo + (16 + lr) * 1024;

  constexpr int K0PAD = NC0 * 32;

#define MFMA6(AH, AL, BO)                                                        \
  {                                                                              \
    half8 w0h = *(const half8*)(bh0 + (BO));                                     \
    half8 w0l = *(const half8*)(bl0 + (BO));                                     \
    half8 w1h = *(const half8*)(bh1 + (BO));                                     \
    half8 w1l = *(const half8*)(bl1 + (BO));                                     \
    acc0  = __builtin_amdgcn_mfma_f32_16x16x32_f16(AH, w0h, acc0, 0, 0, 0);      \
    acc1  = __builtin_amdgcn_mfma_f32_16x16x32_f16(AH, w1h, acc1, 0, 0, 0);      \
    acc0L = __builtin_amdgcn_mfma_f32_16x16x32_f16(AL, w0h, acc0L, 0, 0, 0);     \
    acc1L = __builtin_amdgcn_mfma_f32_16x16x32_f16(AL, w1h, acc1L, 0, 0, 0);     \
    acc0L = __builtin_amdgcn_mfma_f32_16x16x32_f16(AH, w0l, acc0L, 0, 0, 0);     \
    acc1L = __builtin_amdgcn_mfma_f32_16x16x32_f16(AH, w1l, acc1L, 0, 0, 0);     \
  }

  if constexpr (DEC0) {
    // in0 = pred feedback: fp32 [B][8], K padded to 32 (weights rows 8..31 = 0).
    half8 ah = {}, al = {};
    if (lg == 0) {
      const f32x4 v0 = *(const f32x4*)(pr_in + mb * 8);
      const f32x4 v1 = *(const f32x4*)(pr_in + mb * 8 + 4);
      float v[8] = {v0[0], v0[1], v0[2], v0[3], v1[0], v1[1], v1[2], v1[3]};
      #pragma unroll
      for (int j = 0; j < 8; ++j) {
        _Float16 h = (_Float16)v[j];
        ah[j] = h;
        al[j] = (_Float16)((v[j] - (float)h) * LOSCALE);
      }
    }
    MFMA6(ah, al, ((lg << 3) ^ sw));
  } else {
    const u16* a0h = i0h + (size_t)mb * ld0 + lg * 8;
    const u16* a0l = i0l + (size_t)mb * ld0 + lg * 8;
    #pragma unroll 4
    for (int kk = 0; kk < NC0; ++kk) {
      half8 ah = *(const half8*)(a0h + kk * 32);
      half8 al = *(const half8*)(a0l + kk * 32);
      MFMA6(ah, al, (((kk * 4 + lg) << 3) ^ sw));
    }
  }
  {
    const u16* aHh = iHh + (size_t)mb * H_ + lg * 8;
    const u16* aHl = iHl + (size_t)mb * H_ + lg * 8;
    #pragma unroll 4
    for (int kk = 0; kk < 16; ++kk) {
      half8 ah = *(const half8*)(aHh + kk * 32);
      half8 al = *(const half8*)(aHl + kk * 32);
      MFMA6(ah, al, (((K0PAD / 8 + kk * 4 + lg) << 3) ^ sw));
    }
  }
#undef MFMA6

  // fold lo-plane accumulators back (they carry a 2^12 factor)
  #pragma unroll
  for (int i = 0; i < 4; ++i) {
    acc0[i] = fmaf(acc0L[i], LOINV, acc0[i]);
    acc1[i] = fmaf(acc1L[i], LOINV, acc1[i]);
  }

  // gates -> LDS (swizzled 16B chunks: chunk ^= row&7)
  const int mch = (m0 >> 2) + lg;
  *(f32x4*)(gl + lr * 128 + ((mch ^ (lr & 7)) << 2)) = acc0;
  *(f32x4*)(gl + (16 + lr) * 128 + ((mch ^ (lr & 7)) << 2)) = acc1;
  __syncthreads();

  // elementwise: thread owns (batch b, cols c0..c0+1)
  const int b = tid & 127, c0 = (tid >> 7) << 1;
  float hv[2];
  #pragma unroll
  for (int u = 0; u < 2; ++u) {
    const int cc = c0 + u;
    const int bs = b >> 2, bo = b & 3;
    float gi = gl[(cc) * 128 + ((bs ^ (cc & 7)) << 2) + bo] + bias_s[cc];
    float gf = gl[(8 + cc) * 128 + ((bs ^ ((8 + cc) & 7)) << 2) + bo] + bias_s[8 + cc];
    float gg = gl[(16 + cc) * 128 + ((bs ^ ((16 + cc) & 7)) << 2) + bo] + bias_s[16 + cc];
    float go = gl[(24 + cc) * 128 + ((bs ^ ((24 + cc) & 7)) << 2) + bo] + bias_s[24 + cc];
    float cv = sigm(gf) * creg[u] + sigm(gi) * tanhf_(gg);
    creg[u] = cv;
    hv[u] = sigm(go) * tanhf_(cv);
  }
  u16 h0b, l0b, h1b, l1b;
  split16(hv[0], h0b, l0b);
  split16(hv[1], h1b, l1b);
  *(u32*)(ohh + (size_t)b * H_ + j0 + c0) = (u32)h0b | ((u32)h1b << 16);
  *(u32*)(ohl + (size_t)b * H_ + j0 + c0) = (u32)l0b | ((u32)l1b << 16);

  if constexpr (FC) {
    for (int i = tid; i < FOUT_ * B_; i += NTHR) predl[i] = 0.0f;
    __syncthreads();
    #pragma unroll
    for (int f = 0; f < 8; ++f)
      atomicAdd(&predl[b * 8 + f],
                hv[0] * fcw_s[f * 8 + c0] + hv[1] * fcw_s[f * 8 + c0 + 1]);
    __syncthreads();
    for (int i = tid; i < FOUT_ * B_; i += NTHR) atomicAdd(&pr_out[i], predl[i]);
  }
}

__global__ void __launch_bounds__(NTHR, 1) lstm_all(Params p) {
  // LDS: Wb hi/lo 128KB + gates 16KB + pred 4KB + bias/fcw ~0.4KB = ~148.4KB
  __shared__ __align__(16) u16 WbHi[32 * 1024];
  __shared__ __align__(16) u16 WbLo[32 * 1024];
  __shared__ __align__(16) float gl[32 * B_];
  __shared__ float predl[FOUT_ * B_];
  __shared__ float bias_s[32];
  __shared__ float fcw_s[64];

  const int tid = threadIdx.x;
  const int bid = blockIdx.x;
  const int layer = bid >> 6;
  const int j0 = (bid & 63) * 8;

  u16* xb = (u16*)p.ws;                             // [2][T][B][64] fp16 planes
  u16* hbuf = xb + (size_t)2 * T_ * B_ * FIN_;      // [3][2][2][B][512]
  float* pr = (float*)(hbuf + (size_t)12 * B_ * H_);  // [2][B][8] fp32

  cg::grid_group grid = cg::this_grid();

  // ---- init: zero h, init pred buffers, stage x as fp16 hi/lo [t][b][f] ----
  {
    u32* hz = (u32*)hbuf;
    const int n = 12 * B_ * H_ / 2;
    for (int i = bid * NTHR + tid; i < n; i += NBLK * NTHR) hz[i] = 0u;
  }
  if (bid == 0) {
    for (int i = tid; i < FOUT_ * B_; i += NTHR) {
      int b = i >> 3, f = i & 7;
      pr[i] = p.fcb[f];                                      // pred accumulator base
      // dec_in = x[:, -1, :FOUT] -> LAST FEATURE (FIN-1), times 0..7.
      // (r3-r5 bug: read x[b][f][T-1] — feature/time transposed. Fixed.)
      pr[FOUT_ * B_ + i] = p.x[((size_t)b * FIN_ + (FIN_ - 1)) * T_ + f];
    }
  }
  {
    const int n = T_ * B_ * FIN_;
    const size_t XE = (size_t)T_ * B_ * FIN_;
    for (int i = bid * NTHR + tid; i < n; i += NBLK * NTHR) {
      int t = i & 511, f = (i >> 9) & 63, b = i >> 15;   // consecutive t -> coalesced reads
      float v = p.x[((size_t)b * FIN_ + f) * T_ + t];
      u16 hi, lo; split16(v, hi, lo);
      size_t o = ((size_t)t * B_ + b) * FIN_ + f;
      xb[o] = hi;
      xb[XE + o] = lo;
    }
  }
  // stage encoder weights + bias
  if (layer == 0)      stage_w(WbHi, WbLo, p.eWih0, FIN_, FIN_, p.eWhh, j0);
  else if (layer == 1) stage_w(WbHi, WbLo, p.eWih, H_, H_, p.eWhh + (size_t)G4H_ * H_, j0);
  else                 stage_w(WbHi, WbLo, p.eWih + (size_t)G4H_ * H_, H_, H_,
                               p.eWhh + (size_t)2 * G4H_ * H_, j0);
  if (tid < 32) {
    int gr = (tid >> 3) * H_ + j0 + (tid & 7);
    bias_s[tid] = p.ebih[layer * G4H_ + gr] + p.ebhh[layer * G4H_ + gr];
  }
  grid.sync();

  float creg[2] = {0.0f, 0.0f};
  const size_t HB2 = (size_t)B_ * H_;
  const size_t XE = (size_t)T_ * B_ * FIN_;
  auto hbp = [&](int l, int par, int pl) -> u16* {
    return hbuf + (((size_t)l * 2 + par) * 2 + pl) * HB2;
  };

  // ---- Encoder: diagonal pipeline, layer l does t = s - l ----
  for (int s = 0; s < T_ + 2; ++s) {
    int t = s - layer;
    if (t >= 0 && t < T_) {
      int pi = (s - 1) & 1, po = s & 1;
      if (layer == 0) {
        cell<2, false, false>(WbHi, WbLo, gl, predl, bias_s, fcw_s,
                              xb + (size_t)t * B_ * FIN_, xb + XE + (size_t)t * B_ * FIN_,
                              FIN_, nullptr,
                              hbp(0, pi, 0), hbp(0, pi, 1),
                              hbp(0, po, 0), hbp(0, po, 1), j0, creg, nullptr);
      } else {
        cell<16, false, false>(WbHi, WbLo, gl, predl, bias_s, fcw_s,
                               hbp(layer - 1, pi, 0), hbp(layer - 1, pi, 1), H_, nullptr,
                               hbp(layer, pi, 0), hbp(layer, pi, 1),
                               hbp(layer, po, 0), hbp(layer, po, 1), j0, creg, nullptr);
      }
    }
    grid.sync();
  }

  // ---- restage decoder weights/bias/fcw (block-local; Wb readers done) ----
  if (layer == 0)      stage_w(WbHi, WbLo, p.dWih0, FOUT_, 32, p.dWhh, j0);
  else if (layer == 1) stage_w(WbHi, WbLo, p.dWih, H_, H_, p.dWhh + (size_t)G4H_ * H_, j0);
  else                 stage_w(WbHi, WbLo, p.dWih + (size_t)G4H_ * H_, H_, H_,
                               p.dWhh + (size_t)2 * G4H_ * H_, j0);
  if (tid < 32) {
    int gr = (tid >> 3) * H_ + j0 + (tid & 7);
    bias_s[tid] = p.dbih[layer * G4H_ + gr] + p.dbhh[layer * G4H_ + gr];
  }
  if (layer == 2 && tid < 64)
    fcw_s[tid] = p.fcw[(size_t)(tid >> 3) * H_ + j0 + (tid & 7)];
  __syncthreads();

  // ---- Decoder: 3 sync'd phases per step ----
  for (int d = 0; d < WOUT_; ++d) {
    if (layer == 0) {
      cell<1, true, false>(WbHi, WbLo, gl, predl, bias_s, fcw_s,
                           nullptr, nullptr, 0,
                           pr + ((d + 1) & 1) * FOUT_ * B_,
                           hbp(0, (d + 1) & 1, 0), hbp(0, (d + 1) & 1, 1),
                           hbp(0, d & 1, 0), hbp(0, d & 1, 1), j0, creg, nullptr);
    }
    grid.sync();
    if (bid == 128) {  // idle l2 block: emit pred[d-1], then reset accumulator to fc_b
      int q = (d + 1) & 1;
      for (int i = tid; i < FOUT_ * B_; i += NTHR) {
        int b = i >> 3, f = i & 7;
        if (d >= 1)
          p.out[((size_t)b * FOUT_ + f) * WOUT_ + (d - 1)] = pr[q * FOUT_ * B_ + i];
        pr[q * FOUT_ * B_ + i] = p.fcb[f];
      }
    }
    if (layer == 1) {
      cell<16, false, false>(WbHi, WbLo, gl, predl, bias_s, fcw_s,
                             hbp(0, d & 1, 0), hbp(0, d & 1, 1), H_, nullptr,
                             hbp(1, d & 1, 0), hbp(1, d & 1, 1),
                             hbp(1, (d + 1) & 1, 0), hbp(1, (d + 1) & 1, 1), j0, creg,
                             nullptr);
    }
    grid.sync();
    if (layer == 2) {
      cell<16, false, true>(WbHi, WbLo, gl, predl, bias_s, fcw_s,
                            hbp(1, (d + 1) & 1, 0), hbp(1, (d + 1) & 1, 1), H_, nullptr,
                            hbp(2, (d + 1) & 1, 0), hbp(2, (d + 1) & 1, 1),
                            hbp(2, d & 1, 0), hbp(2, d & 1, 1), j0, creg,
                            pr + (d & 1) * FOUT_ * B_);
    }
    grid.sync();
  }

  if (bid == 0) {  // last prediction (step 63, parity 1)
    for (int i = tid; i < FOUT_ * B_; i += NTHR) {
      int b = i >> 3, f = i & 7;
      p.out[((size_t)b * FOUT_ + f) * WOUT_ + (WOUT_ - 1)] = pr[FOUT_ * B_ + i];
    }
  }
}

extern "C" void kernel_launch(void* const* d_in, const int* in_sizes, int n_in,
                              void* d_out, int out_size, void* d_ws, size_t ws_size,
                              hipStream_t stream) {
  (void)in_sizes; (void)n_in; (void)out_size; (void)ws_size;
  Params p;
  p.x     = (const float*)d_in[0];
  p.eWih0 = (const float*)d_in[1];
  p.eWih  = (const float*)d_in[2];
  p.eWhh  = (const float*)d_in[3];
  p.ebih  = (const float*)d_in[4];
  p.ebhh  = (const float*)d_in[5];
  p.dWih0 = (const float*)d_in[6];
  p.dWih  = (const float*)d_in[7];
  p.dWhh  = (const float*)d_in[8];
  p.dbih  = (const float*)d_in[9];
  p.dbhh  = (const float*)d_in[10];
  p.fcw   = (const float*)d_in[11];
  p.fcb   = (const float*)d_in[12];
  p.out   = (float*)d_out;
  p.ws    = (float*)d_ws;
  // ws: xb 16.8MB + h 1.6MB + pr 8KB ~= 18.4MB
  void* args[] = { &p };
  hipLaunchCooperativeKernel((const void*)lstm_all, dim3(NBLK), dim3(NTHR), args, 0,
                             stream);
}

// Round 7
// 21907.590 us; speedup vs baseline: 2.0690x; 1.3132x over previous
//
#include <hip/hip_runtime.h>
#include <hip/hip_cooperative_groups.h>

namespace cg = cooperative_groups;

// Problem dims
#define B_    128
#define H_    512
#define T_    512
#define FIN_  64
#define FOUT_ 8
#define WOUT_ 64
#define G4H_  2048   // 4*H_

// 64 blocks per layer (8 h-cols each = 32 gate rows), 512 threads (8 waves).
#define NBLK  192
#define NTHR  512
#define RD    4      // h ring depth (time-indexed, slot = idx % RD)

typedef __attribute__((ext_vector_type(8))) _Float16 half8;
typedef __attribute__((ext_vector_type(4))) float f32x4;
typedef unsigned short u16;
typedef unsigned int u32;

#define LOSCALE   4096.0f          // 2^12: lifts fp16 lo-plane out of subnormals
#define LOINV     0.000244140625f  // 2^-12

struct Params {
  const float *x, *eWih0, *eWih, *eWhh, *ebih, *ebhh;
  const float *dWih0, *dWih, *dWhh, *dbih, *dbhh, *fcw, *fcb;
  float *out; float *ws;
};

__device__ __forceinline__ float sigm(float x) { return 1.0f / (1.0f + __expf(-x)); }
__device__ __forceinline__ float tanhf_(float x) {
  float e = __expf(-2.0f * fabsf(x));
  return copysignf((1.0f - e) / (1.0f + e), x);
}
__device__ __forceinline__ u16 h2u(_Float16 h) {
  union { _Float16 f; u16 u; } v; v.f = h; return v.u;
}
// fp32 -> fp16 hi + scaled lo (lo = 2^12 * residual, fp16-normal for our ranges)
__device__ __forceinline__ void split16(float w, u16& hi, u16& lo) {
  _Float16 h = (_Float16)w;
  _Float16 l = (_Float16)((w - (float)h) * LOSCALE);
  hi = h2u(h); lo = h2u(l);
}

// ---- flag-based dataflow sync (device-scope; per G16) ----
__device__ __forceinline__ int aload(const int* p) {
  return __hip_atomic_load(p, __ATOMIC_RELAXED, __HIP_MEMORY_SCOPE_AGENT);
}
// Wait until each non-null flag reaches 64 (all 64 blocks of a layer signaled),
// then acquire (cache inv) + block barrier so all threads see fresh data.
__device__ __forceinline__ void wait_all(const int* a, const int* b, const int* c) {
  if (threadIdx.x == 0) {
    while (a && aload(a) < 64) __builtin_amdgcn_s_sleep(1);
    while (b && aload(b) < 64) __builtin_amdgcn_s_sleep(1);
    while (c && aload(c) < 64) __builtin_amdgcn_s_sleep(1);
    __threadfence();   // acquire: invalidate stale L1/L2
  }
  __syncthreads();
}
// All threads' writes done -> release (L2 writeback) -> signal.
__device__ __forceinline__ void signal_f(int* f) {
  __syncthreads();
  if (threadIdx.x == 0) {
    __threadfence();   // release: write back dirty lines
    __hip_atomic_fetch_add(f, 1, __ATOMIC_RELAXED, __HIP_MEMORY_SCOPE_AGENT);
  }
}

// Stage this block's 32 gate rows of [Wi | Wh] into LDS as fp16 hi/lo planes,
// B-fragment order: Wb[n][k], with 16B-chunk XOR swizzle (chunk ^= n&7).
__device__ void stage_w(u16* WbHi, u16* WbLo, const float* Wi, int Kreal, int K0pad,
                        const float* Wh, int j0) {
  const int rowlen = K0pad + H_;
  for (int n = 0; n < 32; ++n) {
    const int gr = (n >> 3) * H_ + j0 + (n & 7);
    const float* s0 = Wi + (size_t)gr * Kreal;
    const float* s1 = Wh + (size_t)gr * H_;
    const int sw = (n & 7) << 3;
    for (int k = threadIdx.x; k < rowlen; k += NTHR) {
      float w = (k < K0pad) ? ((k < Kreal) ? s0[k] : 0.0f) : s1[k - K0pad];
      u16 hi, lo; split16(w, hi, lo);
      int kk = k ^ sw;                    // XOR lives in bits 3..5 (chunk bits)
      WbHi[n * 1024 + kk] = hi;
      WbLo[n * 1024 + kk] = lo;
    }
  }
}

// One LSTM cell step for this block's 8 h-columns (see r6 comments; unchanged).
template <int NC0, bool DEC0, bool FC>
__device__ __forceinline__ void cell(
    const u16* __restrict__ WbHi, const u16* __restrict__ WbLo,
    float* __restrict__ gl, float* __restrict__ predl,
    const float* __restrict__ bias_s, const float* __restrict__ fcw_s,
    const u16* __restrict__ i0h, const u16* __restrict__ i0l, const int ld0,
    const float* __restrict__ pr_in,
    const u16* __restrict__ iHh, const u16* __restrict__ iHl,
    u16* __restrict__ ohh, u16* __restrict__ ohl, const int j0,
    float* __restrict__ creg, float* __restrict__ pr_out) {
  const int tid = threadIdx.x;
  const int lane = tid & 63, lr = lane & 15, lg = lane >> 4;
  const int m0 = (tid >> 6) << 4;      // wave's batch base
  const int mb = m0 + lr;              // this lane's A batch row
  const int sw = (lr & 7) << 3;        // swizzle (same for rows lr and 16+lr)

  f32x4 acc0 = {0.f, 0.f, 0.f, 0.f}, acc1 = {0.f, 0.f, 0.f, 0.f};
  f32x4 acc0L = {0.f, 0.f, 0.f, 0.f}, acc1L = {0.f, 0.f, 0.f, 0.f};

  const u16* bh0 = WbHi + lr * 1024;
  const u16* bl0 = WbLo + lr * 1024;
  const u16* bh1 = WbHi + (16 + lr) * 1024;
  const u16* bl1 = WbLo + (16 + lr) * 1024;

  constexpr int K0PAD = NC0 * 32;

#define MFMA6(AH, AL, BO)                                                        \
  {                                                                              \
    half8 w0h = *(const half8*)(bh0 + (BO));                                     \
    half8 w0l = *(const half8*)(bl0 + (BO));                                     \
    half8 w1h = *(const half8*)(bh1 + (BO));                                     \
    half8 w1l = *(const half8*)(bl1 + (BO));                                     \
    acc0  = __builtin_amdgcn_mfma_f32_16x16x32_f16(AH, w0h, acc0, 0, 0, 0);      \
    acc1  = __builtin_amdgcn_mfma_f32_16x16x32_f16(AH, w1h, acc1, 0, 0, 0);      \
    acc0L = __builtin_amdgcn_mfma_f32_16x16x32_f16(AL, w0h, acc0L, 0, 0, 0);     \
    acc1L = __builtin_amdgcn_mfma_f32_16x16x32_f16(AL, w1h, acc1L, 0, 0, 0);     \
    acc0L = __builtin_amdgcn_mfma_f32_16x16x32_f16(AH, w0l, acc0L, 0, 0, 0);     \
    acc1L = __builtin_amdgcn_mfma_f32_16x16x32_f16(AH, w1l, acc1L, 0, 0, 0);     \
  }

  if constexpr (DEC0) {
    // in0 = pred feedback: fp32 [B][8], K padded to 32 (weights rows 8..31 = 0).
    half8 ah = {}, al = {};
    if (lg == 0) {
      const f32x4 v0 = *(const f32x4*)(pr_in + mb * 8);
      const f32x4 v1 = *(const f32x4*)(pr_in + mb * 8 + 4);
      float v[8] = {v0[0], v0[1], v0[2], v0[3], v1[0], v1[1], v1[2], v1[3]};
      #pragma unroll
      for (int j = 0; j < 8; ++j) {
        _Float16 h = (_Float16)v[j];
        ah[j] = h;
        al[j] = (_Float16)((v[j] - (float)h) * LOSCALE);
      }
    }
    MFMA6(ah, al, ((lg << 3) ^ sw));
  } else {
    const u16* a0h = i0h + (size_t)mb * ld0 + lg * 8;
    const u16* a0l = i0l + (size_t)mb * ld0 + lg * 8;
    #pragma unroll 4
    for (int kk = 0; kk < NC0; ++kk) {
      half8 ah = *(const half8*)(a0h + kk * 32);
      half8 al = *(const half8*)(a0l + kk * 32);
      MFMA6(ah, al, (((kk * 4 + lg) << 3) ^ sw));
    }
  }
  {
    const u16* aHh = iHh + (size_t)mb * H_ + lg * 8;
    const u16* aHl = iHl + (size_t)mb * H_ + lg * 8;
    #pragma unroll 4
    for (int kk = 0; kk < 16; ++kk) {
      half8 ah = *(const half8*)(aHh + kk * 32);
      half8 al = *(const half8*)(aHl + kk * 32);
      MFMA6(ah, al, (((K0PAD / 8 + kk * 4 + lg) << 3) ^ sw));
    }
  }
#undef MFMA6

  // fold lo-plane accumulators back (they carry a 2^12 factor)
  #pragma unroll
  for (int i = 0; i < 4; ++i) {
    acc0[i] = fmaf(acc0L[i], LOINV, acc0[i]);
    acc1[i] = fmaf(acc1L[i], LOINV, acc1[i]);
  }

  // gates -> LDS (swizzled 16B chunks: chunk ^= row&7)
  const int mch = (m0 >> 2) + lg;
  *(f32x4*)(gl + lr * 128 + ((mch ^ (lr & 7)) << 2)) = acc0;
  *(f32x4*)(gl + (16 + lr) * 128 + ((mch ^ (lr & 7)) << 2)) = acc1;
  __syncthreads();

  // elementwise: thread owns (batch b, cols c0..c0+1)
  const int b = tid & 127, c0 = (tid >> 7) << 1;
  float hv[2];
  #pragma unroll
  for (int u = 0; u < 2; ++u) {
    const int cc = c0 + u;
    const int bs = b >> 2, bo = b & 3;
    float gi = gl[(cc) * 128 + ((bs ^ (cc & 7)) << 2) + bo] + bias_s[cc];
    float gf = gl[(8 + cc) * 128 + ((bs ^ ((8 + cc) & 7)) << 2) + bo] + bias_s[8 + cc];
    float gg = gl[(16 + cc) * 128 + ((bs ^ ((16 + cc) & 7)) << 2) + bo] + bias_s[16 + cc];
    float go = gl[(24 + cc) * 128 + ((bs ^ ((24 + cc) & 7)) << 2) + bo] + bias_s[24 + cc];
    float cv = sigm(gf) * creg[u] + sigm(gi) * tanhf_(gg);
    creg[u] = cv;
    hv[u] = sigm(go) * tanhf_(cv);
  }
  u16 h0b, l0b, h1b, l1b;
  split16(hv[0], h0b, l0b);
  split16(hv[1], h1b, l1b);
  *(u32*)(ohh + (size_t)b * H_ + j0 + c0) = (u32)h0b | ((u32)h1b << 16);
  *(u32*)(ohl + (size_t)b * H_ + j0 + c0) = (u32)l0b | ((u32)l1b << 16);

  if constexpr (FC) {
    for (int i = tid; i < FOUT_ * B_; i += NTHR) predl[i] = 0.0f;
    __syncthreads();
    #pragma unroll
    for (int f = 0; f < 8; ++f)
      atomicAdd(&predl[b * 8 + f],
                hv[0] * fcw_s[f * 8 + c0] + hv[1] * fcw_s[f * 8 + c0 + 1]);
    __syncthreads();
    for (int i = tid; i < FOUT_ * B_; i += NTHR) atomicAdd(&pr_out[i], predl[i]);
  }
}

__global__ void __launch_bounds__(NTHR, 1) lstm_all(Params p) {
  __shared__ __align__(16) u16 WbHi[32 * 1024];
  __shared__ __align__(16) u16 WbLo[32 * 1024];
  __shared__ __align__(16) float gl[32 * B_];
  __shared__ float predl[FOUT_ * B_];
  __shared__ float bias_s[32];
  __shared__ float fcw_s[64];

  const int tid = threadIdx.x;
  const int bid = blockIdx.x;
  const int layer = bid >> 6;
  const int j0 = (bid & 63) * 8;
  const size_t HB = (size_t)B_ * H_;

  // ws layout (~23.4MB):
  u16* xb = (u16*)p.ws;                               // [2][T][B][FIN] fp16 planes
  u16* ehb = xb + (size_t)2 * T_ * B_ * FIN_;         // enc ring [3][RD][2][B][H]
  u16* dhb = ehb + (size_t)3 * RD * 2 * HB;           // dec ring [3][RD][2][B][H]
  float* pr = (float*)(dhb + (size_t)3 * RD * 2 * HB);  // [65][B][8] fp32
  int* f_enc = (int*)(pr + (size_t)65 * B_ * FOUT_);  // [3][513]
  int* f_dec = f_enc + 3 * 513;                       // [3][65]
  int* f_pred = f_dec + 3 * 65;                       // [65]

  cg::grid_group grid = cg::this_grid();
  const int gid = bid * NTHR + tid, gstep = NBLK * NTHR;

  // ---- init ----
  // zero enc ring slot 0 (= time idx 0 initial h) for all 3 layers
  for (int i = gid; i < 3 * 65536; i += gstep) {
    int l = i >> 16, off = i & 65535;
    ((u32*)ehb)[(size_t)l * (RD * 65536) + off] = 0u;
  }
  // zero flags
  for (int i = gid; i < 3 * 513 + 3 * 65 + 65; i += gstep) f_enc[i] = 0;
  // pred buffers: idx0 = dec_in (x[:, -1, :FOUT] = last feature, times 0..7);
  // idx 1..64 = fc bias accumulator base.
  for (int i = gid; i < 65 * B_ * FOUT_; i += gstep) {
    int d = i >> 10, r = i & 1023, b = r >> 3, f = r & 7;
    pr[i] = (d == 0) ? p.x[((size_t)b * FIN_ + (FIN_ - 1)) * T_ + f] : p.fcb[f];
  }
  // stage x as fp16 hi/lo [t][b][f]
  {
    const size_t XE0 = (size_t)T_ * B_ * FIN_;
    for (int i = gid; i < T_ * B_ * FIN_; i += gstep) {
      int t = i & 511, f = (i >> 9) & 63, b = i >> 15;
      float v = p.x[((size_t)b * FIN_ + f) * T_ + t];
      u16 hi, lo; split16(v, hi, lo);
      size_t o = ((size_t)t * B_ + b) * FIN_ + f;
      xb[o] = hi;
      xb[XE0 + o] = lo;
    }
  }
  // stage encoder weights + bias
  if (layer == 0)      stage_w(WbHi, WbLo, p.eWih0, FIN_, FIN_, p.eWhh, j0);
  else if (layer == 1) stage_w(WbHi, WbLo, p.eWih, H_, H_, p.eWhh + (size_t)G4H_ * H_, j0);
  else                 stage_w(WbHi, WbLo, p.eWih + (size_t)G4H_ * H_, H_, H_,
                               p.eWhh + (size_t)2 * G4H_ * H_, j0);
  if (tid < 32) {
    int gr = (tid >> 3) * H_ + j0 + (tid & 7);
    bias_s[tid] = p.ebih[layer * G4H_ + gr] + p.ebhh[layer * G4H_ + gr];
  }
  grid.sync();   // the ONLY grid-wide barrier

  float creg[2] = {0.0f, 0.0f};
  const size_t XE = (size_t)T_ * B_ * FIN_;
  auto ep = [&](int l, int idx, int pl) -> u16* {
    return ehb + (((size_t)l * RD + (idx & (RD - 1))) * 2 + pl) * HB;
  };
  auto dp = [&](int l, int idx, int pl) -> u16* {
    return dhb + (((size_t)l * RD + (idx & (RD - 1))) * 2 + pl) * HB;
  };

  // ---- Encoder: per-layer dataflow. Ring idx k = h input for step k.
  // Step t: read sibling idx t (flag f_enc[l][t]), producer idx t+1 of layer l-1
  // (flag f_enc[l-1][t+1]), write idx t+1, signal f_enc[l][t+1].
  // Back-pressure: idx t+1 aliases idx t-3; consumer l+1 read idx t-3 at its
  // step t-4, signaled f_enc[l+1][t-3]. Siblings implied by monotone progress.
  for (int t = 0; t < T_; ++t) {
    const int* wsib = (t >= 1) ? &f_enc[layer * 513 + t] : nullptr;
    const int* wprod = (layer > 0) ? &f_enc[(layer - 1) * 513 + t + 1] : nullptr;
    const int* wbp = (layer < 2 && t >= RD) ? &f_enc[(layer + 1) * 513 + t - (RD - 1)]
                                            : nullptr;
    wait_all(wsib, wprod, wbp);
    if (layer == 0) {
      cell<2, false, false>(WbHi, WbLo, gl, predl, bias_s, fcw_s,
                            xb + (size_t)t * B_ * FIN_, xb + XE + (size_t)t * B_ * FIN_,
                            FIN_, nullptr,
                            ep(0, t, 0), ep(0, t, 1),
                            ep(0, t + 1, 0), ep(0, t + 1, 1), j0, creg, nullptr);
    } else {
      cell<16, false, false>(WbHi, WbLo, gl, predl, bias_s, fcw_s,
                             ep(layer - 1, t + 1, 0), ep(layer - 1, t + 1, 1), H_, nullptr,
                             ep(layer, t, 0), ep(layer, t, 1),
                             ep(layer, t + 1, 0), ep(layer, t + 1, 1), j0, creg, nullptr);
    }
    if (t == T_ - 1) {
      // copy this block's 8 columns of the final h (ring idx 512) to dec idx 0
      __syncthreads();
      const u32* src = (const u32*)ep(layer, T_, 0);
      u32* dst = (u32*)dp(layer, 0, 0);
      for (int i = tid; i < 1024; i += NTHR) {
        int pl = i >> 9, b = (i >> 2) & 127, w = i & 3;
        size_t o = (size_t)pl * (HB >> 1) + (size_t)b * (H_ >> 1) + (j0 >> 1) + w;
        dst[o] = src[o];
      }
      signal_f(&f_dec[layer * 65 + 0]);
    }
    signal_f(&f_enc[layer * 513 + t + 1]);
  }

  // ---- restage decoder weights/bias/fcw (block-local) ----
  if (layer == 0)      stage_w(WbHi, WbLo, p.dWih0, FOUT_, 32, p.dWhh, j0);
  else if (layer == 1) stage_w(WbHi, WbLo, p.dWih, H_, H_, p.dWhh + (size_t)G4H_ * H_, j0);
  else                 stage_w(WbHi, WbLo, p.dWih + (size_t)G4H_ * H_, H_, H_,
                               p.dWhh + (size_t)2 * G4H_ * H_, j0);
  if (tid < 32) {
    int gr = (tid >> 3) * H_ + j0 + (tid & 7);
    bias_s[tid] = p.dbih[layer * G4H_ + gr] + p.dbhh[layer * G4H_ + gr];
  }
  if (layer == 2 && tid < 64)
    fcw_s[tid] = p.fcw[(size_t)(tid >> 3) * H_ + j0 + (tid & 7)];

  // ---- Decoder: 3-stage flag chain per step; dec ring idx k = h input for step k.
  for (int d = 0; d < WOUT_; ++d) {
    if (layer == 0) {
      wait_all((d > 0) ? &f_pred[d] : nullptr,
               &f_dec[0 * 65 + d],
               (d >= RD) ? &f_dec[1 * 65 + d - (RD - 1)] : nullptr);
      cell<1, true, false>(WbHi, WbLo, gl, predl, bias_s, fcw_s,
                           nullptr, nullptr, 0, pr + (size_t)d * B_ * FOUT_,
                           dp(0, d, 0), dp(0, d, 1),
                           dp(0, d + 1, 0), dp(0, d + 1, 1), j0, creg, nullptr);
      signal_f(&f_dec[0 * 65 + d + 1]);
    } else if (layer == 1) {
      wait_all(&f_dec[1 * 65 + d], &f_dec[0 * 65 + d + 1],
               (d >= RD) ? &f_dec[2 * 65 + d - (RD - 1)] : nullptr);
      cell<16, false, false>(WbHi, WbLo, gl, predl, bias_s, fcw_s,
                             dp(0, d + 1, 0), dp(0, d + 1, 1), H_, nullptr,
                             dp(1, d, 0), dp(1, d, 1),
                             dp(1, d + 1, 0), dp(1, d + 1, 1), j0, creg, nullptr);
      signal_f(&f_dec[1 * 65 + d + 1]);
    } else {
      wait_all(&f_dec[2 * 65 + d], &f_dec[1 * 65 + d + 1], nullptr);
      cell<16, false, true>(WbHi, WbLo, gl, predl, bias_s, fcw_s,
                            dp(1, d + 1, 0), dp(1, d + 1, 1), H_, nullptr,
                            dp(2, d, 0), dp(2, d, 1),
                            dp(2, d + 1, 0), dp(2, d + 1, 1), j0, creg,
                            pr + (size_t)(d + 1) * B_ * FOUT_);
      __syncthreads();
      if (tid == 0) {
        __threadfence();
        __hip_atomic_fetch_add(&f_dec[2 * 65 + d + 1], 1, __ATOMIC_RELAXED,
                               __HIP_MEMORY_SCOPE_AGENT);
        __hip_atomic_fetch_add(&f_pred[d + 1], 1, __ATOMIC_RELAXED,
                               __HIP_MEMORY_SCOPE_AGENT);
      }
    }
  }

  // ---- outputs: L0 block k writes out[:, :, k] from pred idx k+1.
  // For k<63 the data was acquired at step k+1's f_pred wait; k==63 waits here.
  if (layer == 0) {
    const int k = bid;
    if (k == WOUT_ - 1) wait_all(&f_pred[WOUT_], nullptr, nullptr);
    const float* s = pr + (size_t)(k + 1) * B_ * FOUT_;
    for (int i = tid; i < B_ * FOUT_; i += NTHR) {
      int b = i >> 3, f = i & 7;
      p.out[((size_t)b * FOUT_ + f) * WOUT_ + k] = s[i];
    }
  }
}

extern "C" void kernel_launch(void* const* d_in, const int* in_sizes, int n_in,
                              void* d_out, int out_size, void* d_ws, size_t ws_size,
                              hipStream_t stream) {
  (void)in_sizes; (void)n_in; (void)out_size; (void)ws_size;
  Params p;
  p.x     = (const float*)d_in[0];
  p.eWih0 = (const float*)d_in[1];
  p.eWih  = (const float*)d_in[2];
  p.eWhh  = (const float*)d_in[3];
  p.ebih  = (const float*)d_in[4];
  p.ebhh  = (const float*)d_in[5];
  p.dWih0 = (const float*)d_in[6];
  p.dWih  = (const float*)d_in[7];
  p.dWhh  = (const float*)d_in[8];
  p.dbih  = (const float*)d_in[9];
  p.dbhh  = (const float*)d_in[10];
  p.fcw   = (const float*)d_in[11];
  p.fcb   = (const float*)d_in[12];
  p.out   = (float*)d_out;
  p.ws    = (float*)d_ws;
  // ws: xb 16.8MB + enc ring 3.1MB + dec ring 3.1MB + pred 0.27MB + flags 7KB
  void* args[] = { &p };
  hipLaunchCooperativeKernel((const void*)lstm_all, dim3(NBLK), dim3(NTHR), args, 0,
                             stream);
}